// Round 1
// baseline (5262.355 us; speedup 1.0000x reference)
//
#include <hip/hip_runtime.h>
#include <hip/hip_bf16.h>
#include <math.h>

#define T_LEN 8192
#define NUM_CH 64
#define HID 256
#define NUM_CLS 40
#define NUM_PROP 1024
#define NUM_PROP_AFTER 256
#define PROP_LEN 128

__device__ __forceinline__ float fsigmoid(float x) {
    return 1.0f / (1.0f + __expf(-x));
}
__device__ __forceinline__ float ftanh(float x) {
    // robust fast tanh: never overflows
    float e = __expf(-2.0f * fabsf(x));
    float t = (1.0f - e) / (1.0f + e);
    return copysignf(t, x);
}

// ---------------------------------------------------------------------------
// Kernel 1: greedy 1-D NMS, stable-sorted selection, emit t0 per kept slot.
// Single block, 1024 threads (thread = one proposal / one sorted position).
// ---------------------------------------------------------------------------
__global__ __launch_bounds__(1024) void nms_kernel(const float* __restrict__ prop,
                                                   int* __restrict__ t0_out) {
    __shared__ float s_s[NUM_PROP];   // starts by original index
    __shared__ float s_sc[NUM_PROP];  // scores by original index
    __shared__ float ss[NUM_PROP];    // starts by sorted rank
    __shared__ float se[NUM_PROP];    // ends by sorted rank
    __shared__ unsigned char sup[NUM_PROP];

    const int tid = threadIdx.x;

    float ps = prop[tid * 3 + 0];
    float pe = prop[tid * 3 + 1];
    float pc = prop[tid * 3 + 2];
    s_s[tid] = ps;
    s_sc[tid] = pc;
    sup[tid] = 0;
    __syncthreads();

    // rank = stable argsort(-scores): count strictly-greater, plus equal with
    // smaller original index.
    int r = 0;
    for (int j = 0; j < NUM_PROP; ++j) {
        float o = s_sc[j];
        r += (o > pc) || (o == pc && j < tid);
    }
    ss[r] = ps;
    se[r] = pe;
    __syncthreads();

    // From here, thread tid represents SORTED position tid.
    const float my_s = ss[tid];
    const float my_e = se[tid];
    const float my_len = my_e - my_s;

    // Greedy sweep (matches reference fori_loop semantics exactly).
    for (int i = 0; i < NUM_PROP; ++i) {
        bool si = (sup[i] != 0);
        if (!si && tid > i) {
            float si_s = ss[i], si_e = se[i];
            float inter = fminf(si_e, my_e) - fmaxf(si_s, my_s);
            inter = fmaxf(inter, 0.0f);
            float uni = (si_e - si_s) + my_len - inter;
            float iou = inter / fmaxf(uni, 1e-6f);
            if (iou > 0.5f) sup[tid] = 1;
        }
        __syncthreads();
    }

    // Stable partition: keeps first (in score order), then suppressed
    // (in score order).  slot = position in that ordering.
    int keep_before = 0, keep_total = 0;
    for (int q = 0; q < NUM_PROP; ++q) {
        int k = (sup[q] == 0) ? 1 : 0;
        keep_total += k;
        if (q < tid) keep_before += k;
    }
    int slot = (sup[tid] == 0) ? keep_before
                               : (keep_total + (tid - keep_before));
    if (slot < NUM_PROP_AFTER) {
        int t0 = (int)rintf(my_s);  // round half-to-even, matches jnp.round
        t0 = max(0, min(t0, T_LEN - PROP_LEN));
        t0_out[slot] = t0;
    }
}

// ---------------------------------------------------------------------------
// Kernel 2: per-sequence LSTM + heads.  One block per kept proposal.
// Thread g (0..1023) owns gate row g: W_ih row (64 f32) + W_hh row (256 f32)
// held in registers for the whole 128-step loop.  h broadcast via LDS.
// ---------------------------------------------------------------------------
__global__ __launch_bounds__(1024, 4) void lstm_kernel(
    const float* __restrict__ data, const int* __restrict__ t0s,
    const float* __restrict__ W_ih, const float* __restrict__ W_hh,
    const float* __restrict__ b_ih, const float* __restrict__ b_hh,
    const float* __restrict__ W_cls, const float* __restrict__ b_cls,
    const float* __restrict__ W_bbox, const float* __restrict__ b_bbox,
    float* __restrict__ out) {
    __shared__ __align__(16) float xbuf[2][NUM_CH];
    __shared__ __align__(16) float hs[HID];
    __shared__ float gates[4 * HID];

    const int tid = threadIdx.x;
    const int b = blockIdx.x;
    const int t0 = t0s[b];

    // Weight rows into registers (read once from L2/L3).
    float4 wih[16];
    {
        const float4* w = (const float4*)(W_ih + tid * NUM_CH);
#pragma unroll
        for (int q = 0; q < 16; ++q) wih[q] = w[q];
    }
    float4 whh[64];
    {
        const float4* w = (const float4*)(W_hh + tid * HID);
#pragma unroll
        for (int q = 0; q < 64; ++q) whh[q] = w[q];
    }
    const float bias = b_ih[tid] + b_hh[tid];

    float c = 0.0f;
    if (tid < HID) hs[tid] = 0.0f;
    if (tid < NUM_CH) xbuf[0][tid] = data[t0 * NUM_CH + tid];
    __syncthreads();

    for (int t = 0; t < PROP_LEN; ++t) {
        const int cur = t & 1;
        float acc = bias;
        const float4* xv4 = (const float4*)&xbuf[cur][0];
#pragma unroll
        for (int q = 0; q < 16; ++q) {
            float4 xv = xv4[q];
            acc += xv.x * wih[q].x + xv.y * wih[q].y + xv.z * wih[q].z +
                   xv.w * wih[q].w;
        }
        const float4* hv4 = (const float4*)&hs[0];
#pragma unroll
        for (int q = 0; q < 64; ++q) {
            float4 hv = hv4[q];
            acc += hv.x * whh[q].x + hv.y * whh[q].y + hv.z * whh[q].z +
                   hv.w * whh[q].w;
        }
        gates[tid] = acc;
        // Prefetch next timestep's x row into the other buffer.
        if (t < PROP_LEN - 1 && tid >= 64 && tid < 128) {
            xbuf[cur ^ 1][tid - 64] = data[(t0 + t + 1) * NUM_CH + (tid - 64)];
        }
        __syncthreads();
        if (tid < HID) {
            float gi = fsigmoid(gates[tid]);
            float gf = fsigmoid(gates[HID + tid]);
            float gg = ftanh(gates[2 * HID + tid]);
            float go = fsigmoid(gates[3 * HID + tid]);
            c = gf * c + gi * gg;
            hs[tid] = go * ftanh(c);
        }
        __syncthreads();
    }

    // Heads: cls (40 outputs) and bbox (80 outputs) per sequence.
    if (tid < NUM_CLS) {
        float a = b_cls[tid];
        const float4* w = (const float4*)(W_cls + tid * HID);
        const float4* hv4 = (const float4*)&hs[0];
#pragma unroll
        for (int q = 0; q < 64; ++q) {
            float4 hv = hv4[q];
            float4 wv = w[q];
            a += hv.x * wv.x + hv.y * wv.y + hv.z * wv.z + hv.w * wv.w;
        }
        out[b * NUM_CLS + tid] = a;
    } else if (tid >= 64 && tid < 64 + 2 * NUM_CLS) {
        const int m = tid - 64;
        float a = b_bbox[m];
        const float4* w = (const float4*)(W_bbox + m * HID);
        const float4* hv4 = (const float4*)&hs[0];
#pragma unroll
        for (int q = 0; q < 64; ++q) {
            float4 hv = hv4[q];
            float4 wv = w[q];
            a += hv.x * wv.x + hv.y * wv.y + hv.z * wv.z + hv.w * wv.w;
        }
        out[NUM_PROP_AFTER * NUM_CLS + b * 2 * NUM_CLS + m] = a;
    }
}

extern "C" void kernel_launch(void* const* d_in, const int* in_sizes, int n_in,
                              void* d_out, int out_size, void* d_ws,
                              size_t ws_size, hipStream_t stream) {
    const float* data = (const float*)d_in[0];     // [8192, 64]
    const float* prop = (const float*)d_in[1];     // [1024, 3]
    const float* W_ih = (const float*)d_in[2];     // [1024, 64]
    const float* W_hh = (const float*)d_in[3];     // [1024, 256]
    const float* b_ih = (const float*)d_in[4];     // [1024]
    const float* b_hh = (const float*)d_in[5];     // [1024]
    const float* W_cls = (const float*)d_in[6];    // [40, 256]
    const float* b_cls = (const float*)d_in[7];    // [40]
    const float* W_bbox = (const float*)d_in[8];   // [80, 256]
    const float* b_bbox = (const float*)d_in[9];   // [80]
    float* out = (float*)d_out;                    // 10240 + 20480 f32
    int* t0s = (int*)d_ws;                         // 256 ints scratch

    nms_kernel<<<1, 1024, 0, stream>>>(prop, t0s);
    lstm_kernel<<<NUM_PROP_AFTER, 1024, 0, stream>>>(
        data, t0s, W_ih, W_hh, b_ih, b_hh, W_cls, b_cls, W_bbox, b_bbox, out);
}

// Round 2
// 1271.072 us; speedup vs baseline: 4.1401x; 4.1401x over previous
//
#include <hip/hip_runtime.h>
#include <math.h>

#define T_LEN 8192
#define NUM_CH 64
#define HID 256
#define NUM_CLS 40
#define NUM_PROP 1024
#define NUM_PROP_AFTER 256
#define PROP_LEN 128
#define MS 4                     // sequences per block
#define NBLK (NUM_PROP_AFTER / MS)
#define NCHUNK 40                // 40 chunks of 8 halves = K=320 (256 h + 64 x)

typedef _Float16 h2_t __attribute__((ext_vector_type(2)));
union U32H2 { unsigned int u; h2_t h; };
union HU16 { _Float16 h; unsigned short u; };

#if defined(__has_builtin)
#if __has_builtin(__builtin_amdgcn_fdot2)
#define HAS_FDOT2 1
#endif
#endif

__device__ __forceinline__ float dot2f(unsigned int wa, unsigned int hb, float acc) {
    U32H2 a, b;
    a.u = wa;
    b.u = hb;
#ifdef HAS_FDOT2
    return __builtin_amdgcn_fdot2(a.h, b.h, acc, false);
#else
    return acc + (float)a.h[0] * (float)b.h[0] + (float)a.h[1] * (float)b.h[1];
#endif
}

__device__ __forceinline__ float dot8f(const uint4& w, const uint4& h, float acc) {
    acc = dot2f(w.x, h.x, acc);
    acc = dot2f(w.y, h.y, acc);
    acc = dot2f(w.z, h.z, acc);
    acc = dot2f(w.w, h.w, acc);
    return acc;
}

__device__ __forceinline__ float fsigmoid(float x) { return 1.0f / (1.0f + __expf(-x)); }
__device__ __forceinline__ float ftanh(float x) {
    float e = __expf(-2.0f * fabsf(x));
    float t = (1.0f - e) / (1.0f + e);
    return copysignf(t, x);
}

// ---------------------------------------------------------------------------
// Pack W_hh|W_ih into f16, K-major chunks: WQ[c][g][8] halves.
// c<32: W_hh[g][c*8+j]; c>=32: W_ih[g][(c-32)*8+j].
// ---------------------------------------------------------------------------
__global__ __launch_bounds__(256) void pack_w(const float* __restrict__ W_ih,
                                              const float* __restrict__ W_hh,
                                              unsigned short* __restrict__ WQ) {
    int e = blockIdx.x * 256 + threadIdx.x;  // 0 .. 327679
    int j = e & 7;
    int g = (e >> 3) & 1023;
    int c = e >> 13;
    float v = (c < 32) ? W_hh[g * HID + c * 8 + j] : W_ih[g * NUM_CH + (c - 32) * 8 + j];
    HU16 hv;
    hv.h = (_Float16)v;
    WQ[(c * 1024 + g) * 8 + j] = hv.u;
}

// ---------------------------------------------------------------------------
// NMS: rank by score, chunk-serial greedy resolution (wave 0) + parallel apply.
// ---------------------------------------------------------------------------
__global__ __launch_bounds__(1024) void nms_kernel(const float* __restrict__ prop,
                                                   int* __restrict__ t0_out) {
    __shared__ float s_sc[NUM_PROP];
    __shared__ float ss[NUM_PROP];
    __shared__ float se[NUM_PROP];
    __shared__ unsigned char sup[NUM_PROP];
    __shared__ unsigned long long cmask[16];

    const int tid = threadIdx.x;
    float ps = prop[tid * 3 + 0];
    float pe = prop[tid * 3 + 1];
    float pc = prop[tid * 3 + 2];
    s_sc[tid] = pc;
    sup[tid] = 0;
    __syncthreads();

    // stable rank in descending-score order
    int r = 0;
    for (int j = 0; j < NUM_PROP; ++j) {
        float o = s_sc[j];
        r += (o > pc) || (o == pc && j < tid);
    }
    ss[r] = ps;
    se[r] = pe;
    __syncthreads();

    const float my_s = ss[tid];
    const float my_e = se[tid];
    const float my_len = my_e - my_s;
    bool mysup = false;

    for (int ci = 0; ci < 16; ++ci) {
        // wave 0 serially resolves intra-chunk suppression
        if (tid < 64) {
            int i = ci * 64 + tid;
            float is_ = ss[i], ie_ = se[i];
            unsigned long long m = __ballot(sup[i] != 0);
            for (int l = 0; l < 64; ++l) {
                if (!((m >> l) & 1)) {  // uniform branch: m is lane-uniform
                    float ls = __shfl(is_, l);
                    float le = __shfl(ie_, l);
                    float inter = fmaxf(fminf(le, ie_) - fmaxf(ls, is_), 0.0f);
                    float uni = (le - ls) + (ie_ - is_) - inter;
                    float iou = inter / fmaxf(uni, 1e-6f);
                    unsigned long long nb = __ballot((tid > l) && (iou > 0.5f));
                    m |= nb;
                }
            }
            sup[i] = (unsigned char)((m >> tid) & 1);
            if (tid == 0) cmask[ci] = ~m;  // alive mask for this chunk
        }
        __syncthreads();
        unsigned long long am = cmask[ci];
        // all threads apply suppression from this chunk's alive members
        for (int l = 0; l < 64; ++l) {
            if ((am >> l) & 1) {  // uniform branch
                int i = ci * 64 + l;
                if (tid > i && !mysup) {
                    float ls = ss[i], le = se[i];
                    float inter = fmaxf(fminf(le, my_e) - fmaxf(ls, my_s), 0.0f);
                    float uni = (le - ls) + my_len - inter;
                    if (inter / fmaxf(uni, 1e-6f) > 0.5f) mysup = true;
                }
            }
        }
        sup[tid] = mysup ? 1 : 0;
        __syncthreads();
    }

    // stable partition via per-chunk alive masks
    int myc = tid >> 6;
    unsigned long long mybit = 1ull << (tid & 63);
    int kb = 0, kt = 0;
    for (int c2 = 0; c2 < 16; ++c2) {
        int p = __popcll(cmask[c2]);
        kt += p;
        if (c2 < myc) kb += p;
    }
    kb += __popcll(cmask[myc] & (mybit - 1));
    int slot = (cmask[myc] & mybit) ? kb : (kt + (tid - kb));
    if (slot < NUM_PROP_AFTER) {
        int t0 = (int)rintf(my_s);
        t0 = max(0, min(t0, T_LEN - PROP_LEN));
        t0_out[slot] = t0;
    }
}

// ---------------------------------------------------------------------------
// LSTM: 64 blocks x 1024 threads; thread = gate row, MS=4 sequences/block.
// W streamed f16 K-major (coalesced dwordx4); h/x as f16 in LDS; c fp32 reg.
// ---------------------------------------------------------------------------
__global__ __launch_bounds__(1024) void lstm_kernel(
    const float* __restrict__ data, const int* __restrict__ t0s,
    const unsigned short* __restrict__ WQ,
    const float* __restrict__ b_ih, const float* __restrict__ b_hh,
    const float* __restrict__ W_cls, const float* __restrict__ b_cls,
    const float* __restrict__ W_bbox, const float* __restrict__ b_bbox,
    float* __restrict__ out) {
    __shared__ __align__(16) _Float16 hx[2][NCHUNK][MS][8];
    __shared__ float gates[MS * 1024];

    const int tid = threadIdx.x;
    const int sbase = blockIdx.x * MS;

    const float bias = b_ih[tid] + b_hh[tid];

    // x-loader role (threads 0..255): seq xs, channel xch
    const int xs = tid >> 6;
    const int xch = tid & 63;
    int xt0 = 0;
    if (tid < 256) xt0 = t0s[sbase + xs];

    // zero h region of buf 0 (chunks 0..31): 32*4*8 = 1024 halves
    {
        int c = tid >> 5, s = (tid >> 3) & 3, j = tid & 7;
        hx[0][c][s][j] = (_Float16)0.0f;
    }
    if (tid < 256) hx[0][32 + (xch >> 3)][xs][xch & 7] = (_Float16)data[xt0 * NUM_CH + xch];

    float c_st = 0.0f;
    const int cs = tid >> 8;   // epilogue seq
    const int ck = tid & 255;  // epilogue hidden unit
    __syncthreads();

    const uint4* wqp = (const uint4*)WQ;  // [c*1024 + g] -> 8 halves

    for (int t = 0; t < PROP_LEN; ++t) {
        const int cur = t & 1, nxt = cur ^ 1;
        // prefetch next x into the other buffer (region disjoint from h writes)
        if (t < PROP_LEN - 1 && tid < 256) {
            hx[nxt][32 + (xch >> 3)][xs][xch & 7] =
                (_Float16)data[(xt0 + t + 1) * NUM_CH + xch];
        }
        float a0 = bias, a1 = bias, a2 = bias, a3 = bias;
#pragma unroll 2
        for (int c = 0; c < NCHUNK; ++c) {
            uint4 w = wqp[c * 1024 + tid];
            uint4 h0 = *(const uint4*)&hx[cur][c][0][0];
            uint4 h1 = *(const uint4*)&hx[cur][c][1][0];
            uint4 h2 = *(const uint4*)&hx[cur][c][2][0];
            uint4 h3 = *(const uint4*)&hx[cur][c][3][0];
            a0 = dot8f(w, h0, a0);
            a1 = dot8f(w, h1, a1);
            a2 = dot8f(w, h2, a2);
            a3 = dot8f(w, h3, a3);
        }
        gates[tid] = a0;
        gates[1024 + tid] = a1;
        gates[2048 + tid] = a2;
        gates[3072 + tid] = a3;
        __syncthreads();

        // epilogue: thread (cs, ck) owns cell state c[cs][ck]
        {
            float gi = fsigmoid(gates[cs * 1024 + ck]);
            float gf = fsigmoid(gates[cs * 1024 + 256 + ck]);
            float gg = ftanh(gates[cs * 1024 + 512 + ck]);
            float go = fsigmoid(gates[cs * 1024 + 768 + ck]);
            c_st = gf * c_st + gi * gg;
            float h = go * ftanh(c_st);
            hx[nxt][ck >> 3][cs][ck & 7] = (_Float16)h;
        }
        __syncthreads();
    }

    // final h lives in hx[0] (t=127: nxt=0). Heads: 480 threads, K=256 dot.
    if (tid < MS * 120) {
        int s = tid / 120;
        int m = tid % 120;
        const float* Wrow;
        float acc;
        int oidx;
        if (m < NUM_CLS) {
            Wrow = W_cls + m * HID;
            acc = b_cls[m];
            oidx = (sbase + s) * NUM_CLS + m;
        } else {
            int mb = m - NUM_CLS;
            Wrow = W_bbox + mb * HID;
            acc = b_bbox[mb];
            oidx = NUM_PROP_AFTER * NUM_CLS + (sbase + s) * 2 * NUM_CLS + mb;
        }
        const float4* w4 = (const float4*)Wrow;
        for (int c = 0; c < 32; ++c) {
            const _Float16* hp = &hx[0][c][s][0];
            float4 wa = w4[c * 2 + 0];
            float4 wb = w4[c * 2 + 1];
            acc += (float)hp[0] * wa.x + (float)hp[1] * wa.y + (float)hp[2] * wa.z +
                   (float)hp[3] * wa.w + (float)hp[4] * wb.x + (float)hp[5] * wb.y +
                   (float)hp[6] * wb.z + (float)hp[7] * wb.w;
        }
        out[oidx] = acc;
    }
}

extern "C" void kernel_launch(void* const* d_in, const int* in_sizes, int n_in,
                              void* d_out, int out_size, void* d_ws,
                              size_t ws_size, hipStream_t stream) {
    const float* data = (const float*)d_in[0];     // [8192, 64]
    const float* prop = (const float*)d_in[1];     // [1024, 3]
    const float* W_ih = (const float*)d_in[2];     // [1024, 64]
    const float* W_hh = (const float*)d_in[3];     // [1024, 256]
    const float* b_ih = (const float*)d_in[4];     // [1024]
    const float* b_hh = (const float*)d_in[5];     // [1024]
    const float* W_cls = (const float*)d_in[6];    // [40, 256]
    const float* b_cls = (const float*)d_in[7];    // [40]
    const float* W_bbox = (const float*)d_in[8];   // [80, 256]
    const float* b_bbox = (const float*)d_in[9];   // [80]
    float* out = (float*)d_out;

    int* t0s = (int*)d_ws;                                         // 1 KB
    unsigned short* WQ = (unsigned short*)((char*)d_ws + 1024);    // 640 KB f16

    pack_w<<<1280, 256, 0, stream>>>(W_ih, W_hh, WQ);
    nms_kernel<<<1, 1024, 0, stream>>>(prop, t0s);
    lstm_kernel<<<NBLK, 1024, 0, stream>>>(data, t0s, WQ, b_ih, b_hh, W_cls,
                                           b_cls, W_bbox, b_bbox, out);
}